// Round 1
// baseline (283.345 us; speedup 1.0000x reference)
//
#include <hip/hip_runtime.h>
#include <hip/hip_bf16.h>

// Problem constants (Qwen3-Next linear attention defaults)
#define S_LEN   256
#define HID     2048
#define NVH     32
#define DKD     128
#define DVD     128
#define KEYDIM  512
#define VALDIM  4096
#define CONVDIM 5120
#define QKVZ_N  9216
#define EPS_F   1e-6f

typedef __attribute__((ext_vector_type(8))) short bf16x8;
typedef __attribute__((ext_vector_type(4))) float f32x4;

__device__ __forceinline__ unsigned short f2bf(float f) {
    union { float f; unsigned int i; } v; v.f = f;
    unsigned int x = v.i;
    return (unsigned short)((x + 0x7FFFu + ((x >> 16) & 1u)) >> 16); // RNE
}
__device__ __forceinline__ unsigned int pk2(float x, float y) {
    union { __hip_bfloat162 h; unsigned int u; } c;
    c.h = __float22bfloat162_rn(float2{x, y});
    return c.u;
}
__device__ __forceinline__ float4 asf4(uint4 u) {
    union { uint4 u; float4 f; } c; c.u = u; return c.f;
}
__device__ __forceinline__ uint2 cvt4(float4 a) {
    uint2 r; r.x = pk2(a.x, a.y); r.y = pk2(a.z, a.w); return r;
}

// ---------------------------------------------------------------------------
// Split-K MFMA GEMM: Cpart[z] = A[M,K-chunk] @ B[N,K-chunk]^T.
// A fp32 (A_F32) or bf16; B fp32 -> bf16 in staging. M fixed 256.
// Block = 512 thr = 8 waves (2Mx4N), tile 128x128, BK=64.
// LDS double-buffered (64 KB), XOR-(row&7) swizzled 16B chunks:
//   conflict-free ds_read_b128 frag reads AND conflict-free staging stores.
// One __syncthreads per K-iter; global loads issued before MFMA of prev tile.
// ---------------------------------------------------------------------------
template<bool A_F32>
__global__ __launch_bounds__(512, 2)
void gemm_tile(const void* __restrict__ Ap, const float* __restrict__ B,
               float* __restrict__ Cpart, int N, int K, int kc) {
    __shared__ __align__(16) unsigned short As[2][128][64];
    __shared__ __align__(16) unsigned short Bs[2][128][64];

    const int tid  = threadIdx.x;
    const int lane = tid & 63, wave = tid >> 6;   // 8 waves
    const int wm = wave >> 2, wn = wave & 3;      // 2 x 4 wave grid
    const int quad = lane >> 4, l16 = lane & 15;
    const int m0 = blockIdx.y * 128, n0 = blockIdx.x * 128;
    const int kbeg = blockIdx.z * kc;
    const int niter = kc >> 6;                    // BK = 64

    // staging coords: fp32 source reads 16B (4 floats) per row-slice
    const int rF = tid >> 4;                      // rows rF + 32*i
    const int cF = (tid & 15) * 4;                // float col (16B granule)
    // bf16 source reads 16B (8 shorts) per row-slice
    const int rH = tid >> 3;                      // rows rH + 64*i
    const int cH = (tid & 7) * 8;                 // short col (16B granule)

    f32x4 acc[4][2];
#pragma unroll
    for (int i = 0; i < 4; i++)
#pragma unroll
        for (int j = 0; j < 2; j++) acc[i][j] = (f32x4){0.f, 0.f, 0.f, 0.f};

    uint4 qa[4], qb[4];

    auto ld_tiles = [&](int kk) {
        if constexpr (A_F32) {
            const float* a = (const float*)Ap + (size_t)(m0 + rF) * K + kk + cF;
#pragma unroll
            for (int i = 0; i < 4; i++)
                qa[i] = *(const uint4*)(a + (size_t)(32 * i) * K);
        } else {
            const unsigned short* a = (const unsigned short*)Ap + (size_t)(m0 + rH) * K + kk + cH;
#pragma unroll
            for (int i = 0; i < 2; i++)
                qa[i] = *(const uint4*)(a + (size_t)(64 * i) * K);
        }
        const float* b = B + (size_t)(n0 + rF) * K + kk + cF;
#pragma unroll
        for (int i = 0; i < 4; i++)
            qb[i] = *(const uint4*)(b + (size_t)(32 * i) * K);
    };

    auto st_tiles = [&](int buf) {
        if constexpr (A_F32) {
#pragma unroll
            for (int i = 0; i < 4; i++) {
                int r = rF + 32 * i;
                int col = ((((tid & 15) >> 1) ^ (r & 7)) << 3) + (tid & 1) * 4;
                *(uint2*)(&As[buf][r][col]) = cvt4(asf4(qa[i]));
            }
        } else {
#pragma unroll
            for (int i = 0; i < 2; i++) {
                int r = rH + 64 * i;
                int col = ((tid & 7) ^ (r & 7)) << 3;
                *(uint4*)(&As[buf][r][col]) = qa[i];
            }
        }
#pragma unroll
        for (int i = 0; i < 4; i++) {
            int r = rF + 32 * i;
            int col = ((((tid & 15) >> 1) ^ (r & 7)) << 3) + (tid & 1) * 4;
            *(uint2*)(&Bs[buf][r][col]) = cvt4(asf4(qb[i]));
        }
    };

    auto compute = [&](int buf) {
#pragma unroll
        for (int ks = 0; ks < 2; ks++) {
            bf16x8 af[4], bfr[2];
#pragma unroll
            for (int i = 0; i < 4; i++) {
                int r = wm * 64 + i * 16 + l16;
                af[i] = *(const bf16x8*)(&As[buf][r][(((ks << 2) | quad) ^ (l16 & 7)) << 3]);
            }
#pragma unroll
            for (int j = 0; j < 2; j++) {
                int r = wn * 32 + j * 16 + l16;
                bfr[j] = *(const bf16x8*)(&Bs[buf][r][(((ks << 2) | quad) ^ (l16 & 7)) << 3]);
            }
#pragma unroll
            for (int i = 0; i < 4; i++)
#pragma unroll
                for (int j = 0; j < 2; j++)
                    acc[i][j] = __builtin_amdgcn_mfma_f32_16x16x32_bf16(af[i], bfr[j], acc[i][j], 0, 0, 0);
        }
    };

    ld_tiles(kbeg);
    st_tiles(0);
    __syncthreads();

    for (int it = 0; it < niter; ++it) {
        if (it + 1 < niter) ld_tiles(kbeg + (it + 1) * 64);
        compute(it & 1);
        if (it + 1 < niter) {
            st_tiles((it + 1) & 1);
            __syncthreads();
        }
    }

    float* C = Cpart + (size_t)blockIdx.z * 256 * N;
#pragma unroll
    for (int i = 0; i < 4; i++)
#pragma unroll
        for (int j = 0; j < 2; j++)
#pragma unroll
            for (int r = 0; r < 4; r++) {
                int row = m0 + wm * 64 + i * 16 + quad * 4 + r;
                int col = n0 + wn * 32 + j * 16 + l16;
                C[(size_t)row * N + col] = acc[i][j][r];
            }
}

// sum P split-K partials (each n floats apart), float4-vectorized
template<int P>
__global__ void reduce_sum(const float* __restrict__ part, float* __restrict__ out, int n) {
    int i = (blockIdx.x * 256 + threadIdx.x) * 4;
    if (i >= n) return;
    float4 s = *(const float4*)(part + i);
#pragma unroll
    for (int p = 1; p < P; p++) {
        float4 v = *(const float4*)(part + (size_t)p * n + i);
        s.x += v.x; s.y += v.y; s.z += v.z; s.w += v.w;
    }
    *(float4*)(out + i) = s;
}

// ba = hidden @ w_ba^T : [256,64]. 256 blocks x 4 waves; wave = K-chunk.
__global__ __launch_bounds__(256)
void ba_proj(const float* __restrict__ hs,
             const float* __restrict__ w_ba,
             float* __restrict__ ba) {
    int s = blockIdx.x;
    int n = threadIdx.x & 63, seg = threadIdx.x >> 6;
    const float* x = hs + (size_t)s * HID + seg * 512;
    const float* w = w_ba + (size_t)n * HID + seg * 512;
    float acc = 0.f;
#pragma unroll 4
    for (int k = 0; k < 512; k += 4) {
        float4 xv = *(const float4*)(x + k);
        float4 wv = *(const float4*)(w + k);
        acc += xv.x * wv.x + xv.y * wv.y + xv.z * wv.z + xv.w * wv.w;
    }
    __shared__ float parts[4][64];
    parts[seg][n] = acc;
    __syncthreads();
    if (threadIdx.x < 64)
        ba[s * 64 + threadIdx.x] = parts[0][threadIdx.x] + parts[1][threadIdx.x]
                                 + parts[2][threadIdx.x] + parts[3][threadIdx.x];
}

// causal depthwise conv (K=4) + silu over qkv channels (cols 0..5119 of qkvz)
__global__ void conv_silu(const float* __restrict__ qkvz,
                          const float* __restrict__ conv_w,
                          float* __restrict__ out) {
    int idx = blockIdx.x * blockDim.x + threadIdx.x;
    if (idx >= S_LEN * CONVDIM) return;
    int s = idx / CONVDIM, c = idx % CONVDIM;
    float acc = 0.f;
#pragma unroll
    for (int j = 0; j < 4; j++) {
        int t = s - 3 + j;
        if (t >= 0) acc += qkvz[(size_t)t * QKVZ_N + c] * conv_w[c * 4 + j];
    }
    out[idx] = acc / (1.f + __expf(-acc)); // silu
}

// scores[n][s][t] = (t<=s) ? (q[s]·k[t]) * DK^-0.5 * sigmoid(beta[t,n]+dt_bias[n]) : 0
// GQA: dot depends only on hk = n>>3 -> compute once, fan out over 8 v-heads.
__global__ __launch_bounds__(256)
void scores_k(const float* __restrict__ conv, const float* __restrict__ ba,
              const float* __restrict__ dt_bias, float* __restrict__ scores) {
    if (blockIdx.x > blockIdx.y) return;
    int hk = blockIdx.z;
    int s0 = blockIdx.y * 16, t0 = blockIdx.x * 16;
    __shared__ float Qs[16][132], Ks[16][132];
    int tid = threadIdx.x;
    int qoff = hk * DKD;
    int koff = KEYDIM + hk * DKD;
    for (int idx = tid; idx < 16 * 128; idx += 256) {
        int i = idx >> 7, d = idx & 127;
        Qs[i][d] = conv[(size_t)(s0 + i) * CONVDIM + qoff + d];
        Ks[i][d] = conv[(size_t)(t0 + i) * CONVDIM + koff + d];
    }
    __syncthreads();
    int tx = tid & 15, ty = tid >> 4;
    int s = s0 + ty, t = t0 + tx;
    float dot = 0.f;
    for (int d = 0; d < 128; d++) dot += Qs[ty][d] * Ks[tx][d];
    float base = (t <= s) ? dot * 0.08838834764831845f : 0.f;
#pragma unroll
    for (int v = 0; v < 8; v++) {
        int n = hk * 8 + v;
        float b = ba[t * 64 + n] + dt_bias[n];
        float bg = 1.f / (1.f + __expf(-b));
        scores[((size_t)n * 256 + s) * 256 + t] = base * bg;
    }
}

// attn[s][n][d] = sum_t scores[n][s][t] * v[t][n][d]
// One block per (16-row s-tile, head): 256 thr, 8 outputs/thread.
__global__ __launch_bounds__(256)
void attn_v(const float* __restrict__ scores, const float* __restrict__ conv,
            float* __restrict__ attn) {
    int n = blockIdx.y, s0 = blockIdx.x * 16;
    int voff = 2 * KEYDIM + n * DVD;
    __shared__ float Ss[16][17];
    __shared__ float Vs[16][132];
    int tid = threadIdx.x, sy = tid >> 4, dx = tid & 15;
    float acc[8] = {0.f, 0.f, 0.f, 0.f, 0.f, 0.f, 0.f, 0.f};
    for (int t0 = 0; t0 <= s0; t0 += 16) {
        Ss[sy][dx] = scores[((size_t)n * 256 + s0 + sy) * 256 + t0 + dx];
        const float* vp = conv + (size_t)(t0 + sy) * CONVDIM + voff + dx * 8;
        *(float4*)&Vs[sy][dx * 8]     = *(const float4*)vp;
        *(float4*)&Vs[sy][dx * 8 + 4] = *(const float4*)(vp + 4);
        __syncthreads();
#pragma unroll
        for (int j = 0; j < 16; j++) {
            float sv = Ss[sy][j];
#pragma unroll
            for (int r = 0; r < 8; r++) acc[r] += sv * Vs[j][dx + 16 * r];
        }
        __syncthreads();
    }
    float* op = attn + ((size_t)(s0 + sy) * NVH + n) * DVD;
#pragma unroll
    for (int r = 0; r < 8; r++) op[dx + 16 * r] = acc[r];
}

// gated RMSNorm over DV + silu(z) gate; emit bf16 for the final MFMA GEMM
__global__ __launch_bounds__(128)
void rmsnorm_gate(const float* __restrict__ attn, const float* __restrict__ qkvz,
                  const float* __restrict__ norm_w,
                  unsigned short* __restrict__ normed) {
    int s = blockIdx.x >> 5, n = blockIdx.x & 31;
    int d = threadIdx.x;
    float x = attn[((size_t)s * NVH + n) * DVD + d];
    float sq = x * x;
#pragma unroll
    for (int off = 32; off > 0; off >>= 1) sq += __shfl_down(sq, off, 64);
    __shared__ float parts[2];
    if ((d & 63) == 0) parts[d >> 6] = sq;
    __syncthreads();
    float ms = (parts[0] + parts[1]) * (1.f / 128.f);
    float inv = rsqrtf(ms + EPS_F);
    float z = qkvz[(size_t)s * QKVZ_N + CONVDIM + n * DVD + d];
    float sz = z / (1.f + __expf(-z));
    float v = x * inv * norm_w[d] * sz;
    normed[((size_t)s * NVH + n) * DVD + d] = f2bf(v);
}

extern "C" void kernel_launch(void* const* d_in, const int* in_sizes, int n_in,
                              void* d_out, int out_size, void* d_ws, size_t ws_size,
                              hipStream_t stream) {
    const float* hs      = (const float*)d_in[0];
    const float* w_qkvz  = (const float*)d_in[1];
    const float* w_ba    = (const float*)d_in[2];
    const float* w_out   = (const float*)d_in[3];
    const float* conv_w  = (const float*)d_in[4];
    const float* dt_bias = (const float*)d_in[5];
    const float* norm_w  = (const float*)d_in[7];

    // Workspace overlay. Front region: long-lived. Region B: scratch1 (steps
    // 1-3) shares space with normed/attn/scores (5-8) and scratch2 (8-9).
    char* ws = (char*)d_ws;
    float* qkvz = (float*)ws;  ws += (size_t)S_LEN * QKVZ_N * 4;    // 9.44 MB
    float* ba   = (float*)ws;  ws += (size_t)S_LEN * 64 * 4;
    float* conv = (float*)ws;  ws += (size_t)S_LEN * CONVDIM * 4;   // 5.24 MB
    char* regB = ws;
    float* scratch1 = (float*)regB;                                  // sk1 x 9.44 MB
    unsigned short* normed = (unsigned short*)regB;                  // 2.10 MB
    float* scratch2 = (float*)(regB + 2097152);                      // sk2 x 2.10 MB
    float* attn   = (float*)(regB + 2097152);                        // 4.19 MB
    float* scores = (float*)(regB + 2097152 + 4194304);              // 8.39 MB

    // split-K config: big needs ~52.5 MB total; fallback proven to fit.
    const bool big = ws_size >= (size_t)54 * 1024 * 1024;
    const int sk1 = big ? 4 : 2;
    const int sk2 = big ? 16 : 8;

    // 1) qkvz partials = X @ Wqkvz^T  (M=256,N=9216,K=2048)
    gemm_tile<true><<<dim3(QKVZ_N / 128, 2, sk1), 512, 0, stream>>>(hs, w_qkvz, scratch1, QKVZ_N, HID, HID / sk1);
    // 2) ba = X @ Wba^T
    ba_proj<<<S_LEN, 256, 0, stream>>>(hs, w_ba, ba);
    // 3) reduce split-K -> qkvz
    if (big) reduce_sum<4><<<(S_LEN * QKVZ_N) / 1024, 256, 0, stream>>>(scratch1, qkvz, S_LEN * QKVZ_N);
    else     reduce_sum<2><<<(S_LEN * QKVZ_N) / 1024, 256, 0, stream>>>(scratch1, qkvz, S_LEN * QKVZ_N);
    // 4) depthwise causal conv + silu
    conv_silu<<<(S_LEN * CONVDIM) / 256, 256, 0, stream>>>(qkvz, conv_w, conv);
    // 5) causal scores (dot once per k-head, fan out over 8 v-heads)
    scores_k<<<dim3(16, 16, 4), 256, 0, stream>>>(conv, ba, dt_bias, scores);
    // 6) attn = scores @ V
    attn_v<<<dim3(16, NVH), 256, 0, stream>>>(scores, conv, attn);
    // 7) gated RMSNorm -> bf16
    rmsnorm_gate<<<S_LEN * NVH, 128, 0, stream>>>(attn, qkvz, norm_w, normed);
    // 8) out partials = normed @ Wout^T (M=256,N=2048,K=4096)
    gemm_tile<false><<<dim3(HID / 128, 2, sk2), 512, 0, stream>>>(normed, w_out, scratch2, HID, VALDIM, VALDIM / sk2);
    // 9) reduce split-K -> d_out (fp32)
    if (big) reduce_sum<16><<<(S_LEN * HID) / 1024, 256, 0, stream>>>(scratch2, (float*)d_out, S_LEN * HID);
    else     reduce_sum<8><<<(S_LEN * HID) / 1024, 256, 0, stream>>>(scratch2, (float*)d_out, S_LEN * HID);
}

// Round 2
// 256.621 us; speedup vs baseline: 1.1041x; 1.1041x over previous
//
#include <hip/hip_runtime.h>
#include <hip/hip_bf16.h>

// Problem constants (Qwen3-Next linear attention defaults)
#define S_LEN   256
#define HID     2048
#define NVH     32
#define DKD     128
#define DVD     128
#define KEYDIM  512
#define VALDIM  4096
#define CONVDIM 5120
#define QKVZ_N  9216
#define EPS_F   1e-6f

typedef __attribute__((ext_vector_type(8))) short bf16x8;
typedef __attribute__((ext_vector_type(4))) float f32x4;

__device__ __forceinline__ unsigned short f2bf(float f) {
    union { float f; unsigned int i; } v; v.f = f;
    unsigned int x = v.i;
    return (unsigned short)((x + 0x7FFFu + ((x >> 16) & 1u)) >> 16); // RNE
}
__device__ __forceinline__ unsigned int pk2(float x, float y) {
    union { __hip_bfloat162 h; unsigned int u; } c;
    c.h = __float22bfloat162_rn(float2{x, y});
    return c.u;
}
__device__ __forceinline__ bf16x8 pack_bf8(float4 lo, float4 hi) {
    union { uint4 u; bf16x8 h; } c;
    c.u.x = pk2(lo.x, lo.y); c.u.y = pk2(lo.z, lo.w);
    c.u.z = pk2(hi.x, hi.y); c.u.w = pk2(hi.z, hi.w);
    return c.h;
}
// 16B global -> LDS DMA. LDS dest = wave-uniform base + lane*16 (linear).
__device__ __forceinline__ void gl_lds16(const void* g, void* l) {
    __builtin_amdgcn_global_load_lds(
        (const __attribute__((address_space(1))) unsigned int*)g,
        (__attribute__((address_space(3))) unsigned int*)l,
        16, 0, 0);
}

// ---------------------------------------------------------------------------
// Stream-N split-K GEMM: Cpart[z] = A[256,Kc] @ B[N,Kc]^T.
// A bf16 [256][K] (pre-converted), B fp32 [N][K] streamed from HBM once.
// Tile: M=256 (full) x NT (64 or 32), BK=64. 256 thr = 4 waves; wave owns
// 64 M-rows x NT cols. Staging via global_load_lds (no staging VGPRs):
//   As bf16 [256][64] (32KB), Bs fp32 [NT][64] (16/8KB) -> 48/40KB, 3-4 blk/CU.
// XOR-(row&7) swizzle applied on the GLOBAL source address (LDS linear, as
// global_load_lds requires); fragment reads use chunk^(l16&7) -> measured
// zero bank conflicts (round-1 empirics, same pattern).
// B is fp32 in LDS; converted to bf16 at fragment read (4 cvt_pk per frag).
// ---------------------------------------------------------------------------
template<int NT>
__global__ __launch_bounds__(256, 3)
void gemm_sn(const unsigned short* __restrict__ A, const float* __restrict__ B,
             float* __restrict__ Cpart, int N, int K, int kc) {
    __shared__ __align__(16) unsigned short As[256][64];
    __shared__ __align__(16) float Bs[NT][64];

    const int tid  = threadIdx.x;
    const int lane = tid & 63, wave = tid >> 6;
    const int quad = lane >> 4, l16 = lane & 15;
    const int n0 = blockIdx.x * NT;
    const int kbeg = blockIdx.y * kc;
    const int niter = kc >> 6;                 // BK = 64
    constexpr int NB = NT / 16;                // N-frags per wave

    // A staging: 8 insts/wave; inst t covers rows wave*64+t*8 .. +7.
    // lane -> row_off = lane>>3, store-chunk = lane&7; source chunk XOR'd.
    const int a_ro = lane >> 3;
    const int a_gc = (lane & 7) ^ a_ro;        // (row&7) == lane>>3 here
    // B staging: NT/16 insts/wave; inst t covers rows wave*(NT/4)+t*4 .. +3.
    const int b_ro = lane >> 4;
    const int b_cs = lane & 15;

    f32x4 acc[4][NB];
#pragma unroll
    for (int i = 0; i < 4; i++)
#pragma unroll
        for (int j = 0; j < NB; j++) acc[i][j] = (f32x4){0.f, 0.f, 0.f, 0.f};

    auto stage = [&](int kk) {
#pragma unroll
        for (int t = 0; t < 8; ++t) {
            int rbase = wave * 64 + t * 8;
            gl_lds16(A + (size_t)(rbase + a_ro) * K + kk + a_gc * 8,
                     &As[rbase][0]);
        }
#pragma unroll
        for (int t = 0; t < NT / 16; ++t) {
            int rbase = wave * (NT / 4) + t * 4;
            int r = rbase + b_ro;
            int gc = b_cs ^ (r & 7);
            gl_lds16(B + (size_t)(n0 + r) * K + kk + gc * 4,
                     &Bs[rbase][0]);
        }
    };

    auto compute = [&]() {
#pragma unroll
        for (int ks = 0; ks < 2; ++ks) {
            bf16x8 af[4];
#pragma unroll
            for (int i = 0; i < 4; ++i) {
                int r = wave * 64 + i * 16 + l16;
                int c = (ks * 4 + quad) ^ (l16 & 7);
                af[i] = *(const bf16x8*)(&As[r][c * 8]);
            }
#pragma unroll
            for (int j = 0; j < NB; ++j) {
                int r = j * 16 + l16;
                int x = l16 & 7;
                int c0 = (ks * 8 + quad * 2) ^ x;
                int c1 = (ks * 8 + quad * 2 + 1) ^ x;
                float4 lo = *(const float4*)(&Bs[r][c0 * 4]);
                float4 hi = *(const float4*)(&Bs[r][c1 * 4]);
                bf16x8 bfr = pack_bf8(lo, hi);
#pragma unroll
                for (int i = 0; i < 4; ++i)
                    acc[i][j] = __builtin_amdgcn_mfma_f32_16x16x32_bf16(af[i], bfr, acc[i][j], 0, 0, 0);
            }
        }
    };

    stage(kbeg);
    for (int it = 0; it < niter; ++it) {
        __syncthreads();                       // drains DMA (vmcnt) + lgkm
        compute();
        if (it + 1 < niter) {
            __syncthreads();                   // all frag reads done
            stage(kbeg + (it + 1) * 64);
        }
    }

    float* C = Cpart + (size_t)blockIdx.y * 256 * N;
#pragma unroll
    for (int i = 0; i < 4; i++)
#pragma unroll
        for (int j = 0; j < NB; j++)
#pragma unroll
            for (int r = 0; r < 4; r++) {
                int row = wave * 64 + i * 16 + quad * 4 + r;
                int col = n0 + j * 16 + l16;
                C[(size_t)row * N + col] = acc[i][j][r];
            }
}

// fp32 -> bf16 row-copy (8 elems/thread)
__global__ __launch_bounds__(256)
void cvt_bf16(const float* __restrict__ in, unsigned short* __restrict__ out, int n8) {
    int i = blockIdx.x * 256 + threadIdx.x;
    if (i >= n8) return;
    const float4* p = (const float4*)in + (size_t)i * 2;
    float4 a = p[0], b = p[1];
    uint4 r;
    r.x = pk2(a.x, a.y); r.y = pk2(a.z, a.w);
    r.z = pk2(b.x, b.y); r.w = pk2(b.z, b.w);
    *((uint4*)out + i) = r;
}

// sum P split-K partials (each n floats apart), float4-vectorized
template<int P>
__global__ void reduce_sum(const float* __restrict__ part, float* __restrict__ out, int n) {
    int i = (blockIdx.x * 256 + threadIdx.x) * 4;
    if (i >= n) return;
    float4 s = *(const float4*)(part + i);
#pragma unroll
    for (int p = 1; p < P; p++) {
        float4 v = *(const float4*)(part + (size_t)p * n + i);
        s.x += v.x; s.y += v.y; s.z += v.z; s.w += v.w;
    }
    *(float4*)(out + i) = s;
}

// ba = hidden @ w_ba^T : [256,64]. 256 blocks x 4 waves; wave = K-chunk.
__global__ __launch_bounds__(256)
void ba_proj(const float* __restrict__ hs,
             const float* __restrict__ w_ba,
             float* __restrict__ ba) {
    int s = blockIdx.x;
    int n = threadIdx.x & 63, seg = threadIdx.x >> 6;
    const float* x = hs + (size_t)s * HID + seg * 512;
    const float* w = w_ba + (size_t)n * HID + seg * 512;
    float acc = 0.f;
#pragma unroll 4
    for (int k = 0; k < 512; k += 4) {
        float4 xv = *(const float4*)(x + k);
        float4 wv = *(const float4*)(w + k);
        acc += xv.x * wv.x + xv.y * wv.y + xv.z * wv.z + xv.w * wv.w;
    }
    __shared__ float parts[4][64];
    parts[seg][n] = acc;
    __syncthreads();
    if (threadIdx.x < 64)
        ba[s * 64 + threadIdx.x] = parts[0][threadIdx.x] + parts[1][threadIdx.x]
                                 + parts[2][threadIdx.x] + parts[3][threadIdx.x];
}

// causal depthwise conv (K=4) + silu over qkv channels (cols 0..5119 of qkvz)
__global__ void conv_silu(const float* __restrict__ qkvz,
                          const float* __restrict__ conv_w,
                          float* __restrict__ out) {
    int idx = blockIdx.x * blockDim.x + threadIdx.x;
    if (idx >= S_LEN * CONVDIM) return;
    int s = idx / CONVDIM, c = idx % CONVDIM;
    float acc = 0.f;
#pragma unroll
    for (int j = 0; j < 4; j++) {
        int t = s - 3 + j;
        if (t >= 0) acc += qkvz[(size_t)t * QKVZ_N + c] * conv_w[c * 4 + j];
    }
    out[idx] = acc / (1.f + __expf(-acc)); // silu
}

// scores[n][s][t] = (t<=s) ? (q[s]·k[t]) * DK^-0.5 * sigmoid(beta[t,n]+dt_bias[n]) : 0
// GQA: dot depends only on hk = n>>3 -> compute once, fan out over 8 v-heads.
__global__ __launch_bounds__(256)
void scores_k(const float* __restrict__ conv, const float* __restrict__ ba,
              const float* __restrict__ dt_bias, float* __restrict__ scores) {
    if (blockIdx.x > blockIdx.y) return;
    int hk = blockIdx.z;
    int s0 = blockIdx.y * 16, t0 = blockIdx.x * 16;
    __shared__ float Qs[16][132], Ks[16][132];
    int tid = threadIdx.x;
    int qoff = hk * DKD;
    int koff = KEYDIM + hk * DKD;
    for (int idx = tid; idx < 16 * 128; idx += 256) {
        int i = idx >> 7, d = idx & 127;
        Qs[i][d] = conv[(size_t)(s0 + i) * CONVDIM + qoff + d];
        Ks[i][d] = conv[(size_t)(t0 + i) * CONVDIM + koff + d];
    }
    __syncthreads();
    int tx = tid & 15, ty = tid >> 4;
    int s = s0 + ty, t = t0 + tx;
    float dot = 0.f;
    for (int d = 0; d < 128; d++) dot += Qs[ty][d] * Ks[tx][d];
    float base = (t <= s) ? dot * 0.08838834764831845f : 0.f;
#pragma unroll
    for (int v = 0; v < 8; v++) {
        int n = hk * 8 + v;
        float b = ba[t * 64 + n] + dt_bias[n];
        float bg = 1.f / (1.f + __expf(-b));
        scores[((size_t)n * 256 + s) * 256 + t] = base * bg;
    }
}

// attn[s][n][d] = sum_t scores[n][s][t] * v[t][n][d]
// One block per (16-row s-tile, head): 256 thr, 8 outputs/thread.
__global__ __launch_bounds__(256)
void attn_v(const float* __restrict__ scores, const float* __restrict__ conv,
            float* __restrict__ attn) {
    int n = blockIdx.y, s0 = blockIdx.x * 16;
    int voff = 2 * KEYDIM + n * DVD;
    __shared__ float Ss[16][17];
    __shared__ float Vs[16][132];
    int tid = threadIdx.x, sy = tid >> 4, dx = tid & 15;
    float acc[8] = {0.f, 0.f, 0.f, 0.f, 0.f, 0.f, 0.f, 0.f};
    for (int t0 = 0; t0 <= s0; t0 += 16) {
        Ss[sy][dx] = scores[((size_t)n * 256 + s0 + sy) * 256 + t0 + dx];
        const float* vp = conv + (size_t)(t0 + sy) * CONVDIM + voff + dx * 8;
        *(float4*)&Vs[sy][dx * 8]     = *(const float4*)vp;
        *(float4*)&Vs[sy][dx * 8 + 4] = *(const float4*)(vp + 4);
        __syncthreads();
#pragma unroll
        for (int j = 0; j < 16; j++) {
            float sv = Ss[sy][j];
#pragma unroll
            for (int r = 0; r < 8; r++) acc[r] += sv * Vs[j][dx + 16 * r];
        }
        __syncthreads();
    }
    float* op = attn + ((size_t)(s0 + sy) * NVH + n) * DVD;
#pragma unroll
    for (int r = 0; r < 8; r++) op[dx + 16 * r] = acc[r];
}

// gated RMSNorm over DV + silu(z) gate; emit bf16 for the final MFMA GEMM
__global__ __launch_bounds__(128)
void rmsnorm_gate(const float* __restrict__ attn, const float* __restrict__ qkvz,
                  const float* __restrict__ norm_w,
                  unsigned short* __restrict__ normed) {
    int s = blockIdx.x >> 5, n = blockIdx.x & 31;
    int d = threadIdx.x;
    float x = attn[((size_t)s * NVH + n) * DVD + d];
    float sq = x * x;
#pragma unroll
    for (int off = 32; off > 0; off >>= 1) sq += __shfl_down(sq, off, 64);
    __shared__ float parts[2];
    if ((d & 63) == 0) parts[d >> 6] = sq;
    __syncthreads();
    float ms = (parts[0] + parts[1]) * (1.f / 128.f);
    float inv = rsqrtf(ms + EPS_F);
    float z = qkvz[(size_t)s * QKVZ_N + CONVDIM + n * DVD + d];
    float sz = z / (1.f + __expf(-z));
    float v = x * inv * norm_w[d] * sz;
    normed[((size_t)s * NVH + n) * DVD + d] = f2bf(v);
}

extern "C" void kernel_launch(void* const* d_in, const int* in_sizes, int n_in,
                              void* d_out, int out_size, void* d_ws, size_t ws_size,
                              hipStream_t stream) {
    const float* hs      = (const float*)d_in[0];
    const float* w_qkvz  = (const float*)d_in[1];
    const float* w_ba    = (const float*)d_in[2];
    const float* w_out   = (const float*)d_in[3];
    const float* conv_w  = (const float*)d_in[4];
    const float* dt_bias = (const float*)d_in[5];
    const float* norm_w  = (const float*)d_in[7];

    // Workspace overlay. Front region: long-lived. Region B: scratch1 (steps
    // 1-3) shares space with normed/attn/scores (5-8) and scratch2 (8-9).
    char* ws = (char*)d_ws;
    float* qkvz = (float*)ws;  ws += (size_t)S_LEN * QKVZ_N * 4;    // 9.44 MB
    float* ba   = (float*)ws;  ws += (size_t)S_LEN * 64 * 4;
    float* conv = (float*)ws;  ws += (size_t)S_LEN * CONVDIM * 4;   // 5.24 MB
    unsigned short* abf = (unsigned short*)ws;
    ws += (size_t)S_LEN * HID * 2;                                   // 1.05 MB (hs in bf16)
    char* regB = ws;
    float* scratch1 = (float*)regB;                                  // sk1 x 9.44 MB
    unsigned short* normed = (unsigned short*)regB;                  // 2.10 MB
    float* scratch2 = (float*)(regB + 2097152);                      // 8 x 2.10 MB
    float* attn   = (float*)(regB + 2097152);                        // 4.19 MB
    float* scores = (float*)(regB + 2097152 + 4194304);              // 8.39 MB

    // split-K config: big path needs ~53.6 MB total; small proven to fit.
    const bool big = ws_size >= (size_t)55 * 1024 * 1024;
    const int sk1 = big ? 4 : 2;

    // 0) hs -> bf16 (A-operand of GEMM1; 1 MB, L2-resident afterwards)
    cvt_bf16<<<(S_LEN * HID / 8) / 256, 256, 0, stream>>>(hs, abf, S_LEN * HID / 8);
    // 1) qkvz partials = X @ Wqkvz^T  (M=256,N=9216,K=2048); B read exactly once
    if (big) gemm_sn<64><<<dim3(QKVZ_N / 64, 4), 256, 0, stream>>>(abf, w_qkvz, scratch1, QKVZ_N, HID, HID / 4);
    else     gemm_sn<64><<<dim3(QKVZ_N / 64, 2), 256, 0, stream>>>(abf, w_qkvz, scratch1, QKVZ_N, HID, HID / 2);
    // 2) ba = X @ Wba^T
    ba_proj<<<S_LEN, 256, 0, stream>>>(hs, w_ba, ba);
    // 3) reduce split-K -> qkvz
    if (big) reduce_sum<4><<<(S_LEN * QKVZ_N) / 1024, 256, 0, stream>>>(scratch1, qkvz, S_LEN * QKVZ_N);
    else     reduce_sum<2><<<(S_LEN * QKVZ_N) / 1024, 256, 0, stream>>>(scratch1, qkvz, S_LEN * QKVZ_N);
    // 4) depthwise causal conv + silu
    conv_silu<<<(S_LEN * CONVDIM) / 256, 256, 0, stream>>>(qkvz, conv_w, conv);
    // 5) causal scores (dot once per k-head, fan out over 8 v-heads)
    scores_k<<<dim3(16, 16, 4), 256, 0, stream>>>(conv, ba, dt_bias, scores);
    // 6) attn = scores @ V
    attn_v<<<dim3(16, NVH), 256, 0, stream>>>(scores, conv, attn);
    // 7) gated RMSNorm -> bf16
    rmsnorm_gate<<<S_LEN * NVH, 128, 0, stream>>>(attn, qkvz, norm_w, normed);
    // 8) out partials = normed @ Wout^T (M=256,N=2048,K=4096), Z=8
    gemm_sn<32><<<dim3(HID / 32, 8), 256, 0, stream>>>(normed, w_out, scratch2, HID, VALDIM, VALDIM / 8);
    // 9) reduce split-K -> d_out (fp32)
    reduce_sum<8><<<(S_LEN * HID) / 1024, 256, 0, stream>>>(scratch2, (float*)d_out, S_LEN * HID);
}

// Round 3
// 244.652 us; speedup vs baseline: 1.1582x; 1.0489x over previous
//
#include <hip/hip_runtime.h>
#include <hip/hip_bf16.h>

// Problem constants (Qwen3-Next linear attention defaults)
#define S_LEN   256
#define HID     2048
#define NVH     32
#define DKD     128
#define DVD     128
#define KEYDIM  512
#define VALDIM  4096
#define CONVDIM 5120
#define QKVZ_N  9216
#define EPS_F   1e-6f

typedef __attribute__((ext_vector_type(8))) short bf16x8;
typedef __attribute__((ext_vector_type(4))) float f32x4;

__device__ __forceinline__ unsigned short f2bf(float f) {
    union { float f; unsigned int i; } v; v.f = f;
    unsigned int x = v.i;
    return (unsigned short)((x + 0x7FFFu + ((x >> 16) & 1u)) >> 16); // RNE
}
__device__ __forceinline__ unsigned int pk2(float x, float y) {
    union { __hip_bfloat162 h; unsigned int u; } c;
    c.h = __float22bfloat162_rn(float2{x, y});
    return c.u;
}
__device__ __forceinline__ bf16x8 pack_bf8(float4 lo, float4 hi) {
    union { uint4 u; bf16x8 h; } c;
    c.u.x = pk2(lo.x, lo.y); c.u.y = pk2(lo.z, lo.w);
    c.u.z = pk2(hi.x, hi.y); c.u.w = pk2(hi.z, hi.w);
    return c.h;
}
// 16B global -> LDS DMA. LDS dest = wave-uniform base + lane*16 (linear).
__device__ __forceinline__ void gl_lds16(const void* g, void* l) {
    __builtin_amdgcn_global_load_lds(
        (const __attribute__((address_space(1))) unsigned int*)g,
        (__attribute__((address_space(3))) unsigned int*)l,
        16, 0, 0);
}

// ---------------------------------------------------------------------------
// 2-phase double-buffered split-K GEMM: Cpart[z] = A[256,Kc] @ B[N,Kc]^T.
// A bf16 [256][K], B fp32 [N][K] (streamed once; bf16-converted at frag read).
// Tile: 128(M) x 64(N), BK=64. 256 thr = 4 waves (2Mx2N); wave = 64x32.
// LDS: As[2][128][64] bf16 (32KB) + Bs[2][64][64] fp32 (32KB) = 64KB, 2 blk/CU.
// Loop: stage(next buf) ISSUED BEFORE compute(cur) -> DMA latency hides under
// MFMA; ONE barrier per K-step (T3 minimum 2-phase; fixes round-2's serial
// stage->drain->compute).  XOR-(row&7) swizzle on the GLOBAL source (LDS dest
// linear per global_load_lds), frag reads XOR back: A b128 reads measured 0
// conflicts; B fp32 float4 reads cost +4cy each (measured, accepted).
// ---------------------------------------------------------------------------
template<int NT>
__global__ __launch_bounds__(256, 2)
void gemm_db(const unsigned short* __restrict__ A, const float* __restrict__ B,
             float* __restrict__ Cpart, int N, int K, int kc) {
    __shared__ __align__(16) unsigned short As[2][128][64];
    __shared__ __align__(16) float Bs[2][NT][64];

    const int tid  = threadIdx.x;
    const int lane = tid & 63, wave = tid >> 6;
    const int wm = wave >> 1, wn = wave & 1;
    const int quad = lane >> 4, l16 = lane & 15;
    const int m0 = blockIdx.y * 128, n0 = blockIdx.x * NT;
    const int kbeg = blockIdx.z * kc;
    const int niter = kc >> 6;                 // BK = 64

    // A staging: 4 insts/wave; inst t covers rows wave*32+t*8 (+lane>>3).
    const int a_ro = lane >> 3;
    const int a_gc = (lane & 7) ^ a_ro;        // row&7 == lane>>3 (base%8==0)
    // B staging: NT/16 insts/wave; inst t covers rows wave*(NT/4)+t*4 (+lane>>4).
    const int b_ro = lane >> 4;
    const int b_cs = lane & 15;

    f32x4 acc[4][2];
#pragma unroll
    for (int i = 0; i < 4; i++)
#pragma unroll
        for (int j = 0; j < 2; j++) acc[i][j] = (f32x4){0.f, 0.f, 0.f, 0.f};

    auto stage = [&](int buf, int kk) {
#pragma unroll
        for (int t = 0; t < 4; ++t) {
            int rbase = wave * 32 + t * 8;
            gl_lds16(A + (size_t)(m0 + rbase + a_ro) * K + kk + a_gc * 8,
                     &As[buf][rbase][0]);
        }
#pragma unroll
        for (int t = 0; t < NT / 16; ++t) {
            int rbase = wave * (NT / 4) + t * 4;
            int r = rbase + b_ro;
            int gc = b_cs ^ (r & 7);
            gl_lds16(B + (size_t)(n0 + r) * K + kk + gc * 4,
                     &Bs[buf][rbase][0]);
        }
    };

    auto compute = [&](int buf) {
#pragma unroll
        for (int ks = 0; ks < 2; ++ks) {
            bf16x8 af[4];
#pragma unroll
            for (int i = 0; i < 4; ++i) {
                int r = wm * 64 + i * 16 + l16;
                int c = (ks * 4 + quad) ^ (l16 & 7);
                af[i] = *(const bf16x8*)(&As[buf][r][c * 8]);
            }
#pragma unroll
            for (int j = 0; j < 2; ++j) {
                int r = wn * 32 + j * 16 + l16;
                int x = l16 & 7;
                int c0 = (ks * 8 + quad * 2) ^ x;
                int c1 = (ks * 8 + quad * 2 + 1) ^ x;
                float4 lo = *(const float4*)(&Bs[buf][r][c0 * 4]);
                float4 hi = *(const float4*)(&Bs[buf][r][c1 * 4]);
                bf16x8 bfr = pack_bf8(lo, hi);
#pragma unroll
                for (int i = 0; i < 4; ++i)
                    acc[i][j] = __builtin_amdgcn_mfma_f32_16x16x32_bf16(af[i], bfr, acc[i][j], 0, 0, 0);
            }
        }
    };

    stage(0, kbeg);
    __syncthreads();                           // buf0 ready
    for (int it = 0; it < niter; ++it) {
        if (it + 1 < niter) stage((it + 1) & 1, kbeg + (it + 1) * 64);
        compute(it & 1);                       // overlaps in-flight DMA
        __syncthreads();                       // next buf ready; cur reads done
    }

    float* C = Cpart + (size_t)blockIdx.z * 256 * N;
#pragma unroll
    for (int i = 0; i < 4; i++)
#pragma unroll
        for (int j = 0; j < 2; j++)
#pragma unroll
            for (int r = 0; r < 4; r++) {
                int row = m0 + wm * 64 + i * 16 + quad * 4 + r;
                int col = n0 + wn * 32 + j * 16 + l16;
                C[(size_t)row * N + col] = acc[i][j][r];
            }
}

// sum P split-K partials (each n floats apart), float4-vectorized
template<int P>
__global__ void reduce_sum(const float* __restrict__ part, float* __restrict__ out, int n) {
    int i = (blockIdx.x * 256 + threadIdx.x) * 4;
    if (i >= n) return;
    float4 s = *(const float4*)(part + i);
#pragma unroll
    for (int p = 1; p < P; p++) {
        float4 v = *(const float4*)(part + (size_t)p * n + i);
        s.x += v.x; s.y += v.y; s.z += v.z; s.w += v.w;
    }
    *(float4*)(out + i) = s;
}

// ba = hidden @ w_ba^T : [256,64] + emit hs row in bf16 (A of GEMM1).
__global__ __launch_bounds__(256)
void ba_proj_cvt(const float* __restrict__ hs, const float* __restrict__ w_ba,
                 float* __restrict__ ba, unsigned short* __restrict__ abf) {
    int s = blockIdx.x;
    int n = threadIdx.x & 63, seg = threadIdx.x >> 6;
    const float* x = hs + (size_t)s * HID + seg * 512;
    const float* w = w_ba + (size_t)n * HID + seg * 512;
    float acc = 0.f;
#pragma unroll 4
    for (int k = 0; k < 512; k += 4) {
        float4 xv = *(const float4*)(x + k);
        float4 wv = *(const float4*)(w + k);
        acc += xv.x * wv.x + xv.y * wv.y + xv.z * wv.z + xv.w * wv.w;
    }
    __shared__ float parts[4][64];
    parts[seg][n] = acc;
    {   // bf16 copy of this row: thread converts 8 elems (L1-hot reread)
        int d = threadIdx.x * 8;
        const float4* p = (const float4*)(hs + (size_t)s * HID + d);
        float4 a = p[0], b = p[1];
        uint4 r;
        r.x = pk2(a.x, a.y); r.y = pk2(a.z, a.w);
        r.z = pk2(b.x, b.y); r.w = pk2(b.z, b.w);
        *(uint4*)(abf + (size_t)s * HID + d) = r;
    }
    __syncthreads();
    if (threadIdx.x < 64)
        ba[s * 64 + threadIdx.x] = parts[0][threadIdx.x] + parts[1][threadIdx.x]
                                 + parts[2][threadIdx.x] + parts[3][threadIdx.x];
}

// Fused: split-K sum of qkvz partials + causal depthwise conv(K=4) + silu for
// qkv cols (<5120), plain sum for z cols (>=5120, compact zs buffer).
// Thread = 4 cols (float4); block = 1024 cols x 16 s; conv window in regs.
template<int P>
__global__ __launch_bounds__(256)
void sum_conv(const float* __restrict__ part, const float* __restrict__ conv_w,
              float* __restrict__ conv, float* __restrict__ zs) {
    const int s0 = blockIdx.y * 16;
    const int c  = blockIdx.x * 1024 + threadIdx.x * 4;
    auto sum4 = [&](int s) {
        const float* p = part + (size_t)s * QKVZ_N + c;
        float4 v = *(const float4*)p;
#pragma unroll
        for (int q = 1; q < P; q++) {
            float4 w = *(const float4*)(p + (size_t)q * S_LEN * QKVZ_N);
            v.x += w.x; v.y += w.y; v.z += w.z; v.w += w.w;
        }
        return v;
    };
    if (c < CONVDIM) {
        float4 cw[4];
#pragma unroll
        for (int i = 0; i < 4; ++i) cw[i] = *(const float4*)(conv_w + (size_t)(c + i) * 4);
        float4 w0{0,0,0,0}, w1{0,0,0,0}, w2{0,0,0,0};
        for (int s = (s0 >= 3 ? s0 - 3 : 0); s < s0; ++s) { w0 = w1; w1 = w2; w2 = sum4(s); }
        for (int s = s0; s < s0 + 16; ++s) {
            float4 w3 = sum4(s);
            float4 o;
            o.x = w0.x * cw[0].x + w1.x * cw[0].y + w2.x * cw[0].z + w3.x * cw[0].w;
            o.y = w0.y * cw[1].x + w1.y * cw[1].y + w2.y * cw[1].z + w3.y * cw[1].w;
            o.z = w0.z * cw[2].x + w1.z * cw[2].y + w2.z * cw[2].z + w3.z * cw[2].w;
            o.w = w0.w * cw[3].x + w1.w * cw[3].y + w2.w * cw[3].z + w3.w * cw[3].w;
            o.x = o.x / (1.f + __expf(-o.x));
            o.y = o.y / (1.f + __expf(-o.y));
            o.z = o.z / (1.f + __expf(-o.z));
            o.w = o.w / (1.f + __expf(-o.w));
            *(float4*)(conv + (size_t)s * CONVDIM + c) = o;
            w0 = w1; w1 = w2; w2 = w3;
        }
    } else {
        for (int s = s0; s < s0 + 16; ++s) {
            float4 v = sum4(s);
            *(float4*)(zs + (size_t)s * VALDIM + (c - CONVDIM)) = v;
        }
    }
}

// scores[n][s][t] = (t<=s) ? (q[s]·k[t]) * DK^-0.5 * sigmoid(beta[t,n]+dt_bias[n]) : 0
// GQA: dot depends only on hk = n>>3 -> compute once, fan out over 8 v-heads.
__global__ __launch_bounds__(256)
void scores_k(const float* __restrict__ conv, const float* __restrict__ ba,
              const float* __restrict__ dt_bias, float* __restrict__ scores) {
    if (blockIdx.x > blockIdx.y) return;
    int hk = blockIdx.z;
    int s0 = blockIdx.y * 16, t0 = blockIdx.x * 16;
    __shared__ float Qs[16][132], Ks[16][132];
    int tid = threadIdx.x;
    int qoff = hk * DKD;
    int koff = KEYDIM + hk * DKD;
    for (int idx = tid; idx < 16 * 128; idx += 256) {
        int i = idx >> 7, d = idx & 127;
        Qs[i][d] = conv[(size_t)(s0 + i) * CONVDIM + qoff + d];
        Ks[i][d] = conv[(size_t)(t0 + i) * CONVDIM + koff + d];
    }
    __syncthreads();
    int tx = tid & 15, ty = tid >> 4;
    int s = s0 + ty, t = t0 + tx;
    float dot = 0.f;
    for (int d = 0; d < 128; d++) dot += Qs[ty][d] * Ks[tx][d];
    float base = (t <= s) ? dot * 0.08838834764831845f : 0.f;
#pragma unroll
    for (int v = 0; v < 8; v++) {
        int n = hk * 8 + v;
        float b = ba[t * 64 + n] + dt_bias[n];
        float bg = 1.f / (1.f + __expf(-b));
        scores[((size_t)n * 256 + s) * 256 + t] = base * bg;
    }
}

// Fused attn + gated RMSNorm: attn[s][n][:] = sum_t scores[n][s][t]*v[t][n][:]
// stays in registers; 16-lane shfl_xor gives the row sum-of-squares; gate with
// silu(z); emit bf16 directly (kills the 8192-block rmsnorm launch + attn I/O).
__global__ __launch_bounds__(256)
void attn_rms(const float* __restrict__ scores, const float* __restrict__ conv,
              const float* __restrict__ zs, const float* __restrict__ norm_w,
              unsigned short* __restrict__ normed) {
    int n = blockIdx.y, s0 = blockIdx.x * 16;
    int voff = 2 * KEYDIM + n * DVD;
    __shared__ float Ss[16][17];
    __shared__ float Vs[16][132];
    int tid = threadIdx.x, sy = tid >> 4, dx = tid & 15;
    float acc[8] = {0.f, 0.f, 0.f, 0.f, 0.f, 0.f, 0.f, 0.f};
    for (int t0 = 0; t0 <= s0; t0 += 16) {
        Ss[sy][dx] = scores[((size_t)n * 256 + s0 + sy) * 256 + t0 + dx];
        const float* vp = conv + (size_t)(t0 + sy) * CONVDIM + voff + dx * 8;
        *(float4*)&Vs[sy][dx * 8]     = *(const float4*)vp;
        *(float4*)&Vs[sy][dx * 8 + 4] = *(const float4*)(vp + 4);
        __syncthreads();
#pragma unroll
        for (int j = 0; j < 16; j++) {
            float sv = Ss[sy][j];
#pragma unroll
            for (int r = 0; r < 8; r++) acc[r] += sv * Vs[j][dx + 16 * r];
        }
        __syncthreads();
    }
    float ssq = 0.f;
#pragma unroll
    for (int r = 0; r < 8; r++) ssq += acc[r] * acc[r];
#pragma unroll
    for (int m = 1; m <= 8; m <<= 1) ssq += __shfl_xor(ssq, m, 64); // 16-lane group
    float inv = rsqrtf(ssq * (1.f / 128.f) + EPS_F);
    int s = s0 + sy;
#pragma unroll
    for (int r = 0; r < 8; r++) {
        int d = dx + 16 * r;
        float z = zs[(size_t)s * VALDIM + n * DVD + d];
        float sz = z / (1.f + __expf(-z));
        float v = acc[r] * inv * norm_w[d] * sz;
        normed[((size_t)s * NVH + n) * DVD + d] = f2bf(v);
    }
}

extern "C" void kernel_launch(void* const* d_in, const int* in_sizes, int n_in,
                              void* d_out, int out_size, void* d_ws, size_t ws_size,
                              hipStream_t stream) {
    const float* hs      = (const float*)d_in[0];
    const float* w_qkvz  = (const float*)d_in[1];
    const float* w_ba    = (const float*)d_in[2];
    const float* w_out   = (const float*)d_in[3];
    const float* conv_w  = (const float*)d_in[4];
    const float* dt_bias = (const float*)d_in[5];
    const float* norm_w  = (const float*)d_in[7];

    // Workspace overlay. Front: long-lived (abf, ba, conv, zs ~10.1 MB).
    // Region B: scratch1 (gemm1 partials) shares space with
    // normed/scratch2/scores (later stages).
    char* ws = (char*)d_ws;
    unsigned short* abf = (unsigned short*)ws; ws += (size_t)S_LEN * HID * 2;     // 1.05 MB
    float* ba   = (float*)ws;  ws += (size_t)S_LEN * 64 * 4;                      // 64 KB
    float* conv = (float*)ws;  ws += (size_t)S_LEN * CONVDIM * 4;                 // 5.24 MB
    float* zs   = (float*)ws;  ws += (size_t)S_LEN * VALDIM * 4;                  // 4.19 MB
    char* regB = ws;
    const bool big = ws_size >= (size_t)50 * 1024 * 1024;
    const int sk1 = big ? 4 : 2;   // gemm1 split-K
    const int sk2 = big ? 8 : 4;   // gemm2 split-K
    float* scratch1 = (float*)regB;                                   // sk1 x 9.44 MB
    unsigned short* normed = (unsigned short*)regB;                   // 2.10 MB
    float* scratch2 = (float*)(regB + 2097152);                       // sk2 x 2.10 MB
    float* scores   = (float*)(regB + 2097152 + (size_t)sk2 * 2097152); // 8.39 MB

    // 1) ba = X @ Wba^T  and hs -> bf16 A-operand
    ba_proj_cvt<<<S_LEN, 256, 0, stream>>>(hs, w_ba, ba, abf);
    // 2) qkvz partials = X @ Wqkvz^T  (M=256,N=9216,K=2048); B streamed once
    gemm_db<64><<<dim3(QKVZ_N / 64, 2, sk1), 256, 0, stream>>>(abf, w_qkvz, scratch1, QKVZ_N, HID, HID / sk1);
    // 3) fused split-K sum + causal conv + silu (qkv) / plain sum (z)
    if (big) sum_conv<4><<<dim3(9, 16), 256, 0, stream>>>(scratch1, conv_w, conv, zs);
    else     sum_conv<2><<<dim3(9, 16), 256, 0, stream>>>(scratch1, conv_w, conv, zs);
    // 4) causal scores (dot once per k-head, fan out over 8 v-heads)
    scores_k<<<dim3(16, 16, 4), 256, 0, stream>>>(conv, ba, dt_bias, scores);
    // 5) fused attn + gated RMSNorm -> bf16
    attn_rms<<<dim3(16, NVH), 256, 0, stream>>>(scores, conv, zs, norm_w, normed);
    // 6) out partials = normed @ Wout^T (M=256,N=2048,K=4096)
    gemm_db<64><<<dim3(HID / 64, 2, sk2), 256, 0, stream>>>(normed, w_out, scratch2, HID, VALDIM, VALDIM / sk2);
    // 7) reduce split-K -> d_out (fp32)
    if (big) reduce_sum<8><<<(S_LEN * HID) / 1024, 256, 0, stream>>>(scratch2, (float*)d_out, S_LEN * HID);
    else     reduce_sum<4><<<(S_LEN * HID) / 1024, 256, 0, stream>>>(scratch2, (float*)d_out, S_LEN * HID);
}